// Round 4
// baseline (2737.285 us; speedup 1.0000x reference)
//
#include <hip/hip_runtime.h>

#define D 256
typedef unsigned short u16;
using short8  = __attribute__((ext_vector_type(8))) short;
using ushort8 = __attribute__((ext_vector_type(8))) unsigned short;
using f32x4   = __attribute__((ext_vector_type(4))) float;

#define NB 13          // dst-range bins (8192 nodes each)
#define SUBW 64        // sub-cursors per bin
#define SUBCAP 5200    // capacity per sub-region (avg 3846, 21-sigma margin)

__device__ __forceinline__ u16 f2bf(float f) {
    unsigned u = __float_as_uint(f);
    unsigned r = (u + 0x7FFFu + ((u >> 16) & 1u)) >> 16;
    return (u16)r;
}
__device__ __forceinline__ float bf2f(u16 v) {
    return __uint_as_float(((unsigned)v) << 16);
}

__device__ __forceinline__ void load_lds16(const u16* g, u16* l) {
    __builtin_amdgcn_global_load_lds(
        (const __attribute__((address_space(1))) void*)g,
        (__attribute__((address_space(3))) void*)l, 16, 0, 0);
}

// ---------------- CSR build: two-level binning ----------------

__global__ void k_initsub(int* __restrict__ subcur) {
    int i = blockIdx.x * blockDim.x + threadIdx.x;
    if (i < NB * SUBW) subcur[i] = i * SUBCAP;
}

// level 1: degree histogram + append packed edge into dst-range bin.
// bin writes per (wave, bin) are sequential -> full-line writebacks.
__global__ void k_bin(const int* __restrict__ src, const int* __restrict__ dst,
                      int* __restrict__ deg, int* __restrict__ subcur,
                      unsigned* __restrict__ bins, int E) {
    int e = blockIdx.x * blockDim.x + threadIdx.x;
    if (e >= E) return;
    int swid = (blockIdx.x * 4 + (threadIdx.x >> 6)) & (SUBW - 1);
    int d = dst[e], s = src[e];
    atomicAdd(&deg[d], 1);
    int b = d >> 13;
    int pos = atomicAdd(&subcur[b * SUBW + swid], 1);
    bins[pos] = (unsigned)s | ((unsigned)(d & 8191) << 17);
}

__global__ void k_blocksum(const int* __restrict__ deg, int* __restrict__ bsum, int n) {
    __shared__ int s[256];
    int b = blockIdx.x, t = threadIdx.x;
    int base = b * 1024;
    int v = 0;
    for (int i = t; i < 1024; i += 256) {
        int idx = base + i;
        if (idx < n) v += deg[idx];
    }
    s[t] = v;
    __syncthreads();
    for (int off = 128; off > 0; off >>= 1) {
        if (t < off) s[t] += s[t + off];
        __syncthreads();
    }
    if (t == 0) bsum[b] = s[0];
}

__global__ void k_scanbsum(int* bsum, int nb, int* offs, int n, int total) {
    if (threadIdx.x == 0 && blockIdx.x == 0) {
        int run = 0;
        for (int i = 0; i < nb; i++) { int v = bsum[i]; bsum[i] = run; run += v; }
        offs[n] = total;
    }
}

__global__ void k_scanwrite(const int* __restrict__ deg, const int* __restrict__ bsum,
                            int* __restrict__ offs, int* __restrict__ cursor, int n) {
    __shared__ int s[256];
    int b = blockIdx.x, t = threadIdx.x;
    int base = b * 1024 + t * 4;
    int v[4];
    int sum = 0;
    #pragma unroll
    for (int j = 0; j < 4; j++) {
        int idx = base + j;
        v[j] = (idx < n) ? deg[idx] : 0;
        sum += v[j];
    }
    s[t] = sum;
    __syncthreads();
    for (int off = 1; off < 256; off <<= 1) {
        int xv = (t >= off) ? s[t - off] : 0;
        __syncthreads();
        s[t] += xv;
        __syncthreads();
    }
    int excl = s[t] - sum + bsum[b];
    #pragma unroll
    for (int j = 0; j < 4; j++) {
        int idx = base + j;
        if (idx < n) { offs[idx] = excl; cursor[idx] = excl; excl += v[j]; }
    }
}

// level 2: block j drains sub-region j; bin-major block order keeps the
// srcs write window small and L2-resident.
__global__ void k_scat2(const unsigned* __restrict__ bins, const int* __restrict__ subcur,
                        int* __restrict__ cursor, int* __restrict__ srcs) {
    int j = blockIdx.x;
    int b = j >> 6;
    int base = j * SUBCAP;
    int endp = subcur[j];
    for (int i = base + threadIdx.x; i < endp; i += blockDim.x) {
        unsigned v = bins[i];
        int s = (int)(v & 0x1FFFFu);
        int d = (int)(v >> 17) + (b << 13);
        int p = atomicAdd(&cursor[d], 1);
        srcs[p] = s;
    }
}

// ---------------- embedding gather -> bf16 ----------------

__global__ void k_gather_bf(const int* __restrict__ x, const float* __restrict__ emb,
                            u16* __restrict__ h, int N) {
    int idx = blockIdx.x * blockDim.x + threadIdx.x;
    if (idx >= N * 64) return;
    int node = idx >> 6, c = idx & 63;
    int s = x[node];
    float4 v = ((const float4*)emb)[(size_t)s * 64 + c];
    ushort4 o;
    o.x = f2bf(v.x); o.y = f2bf(v.y); o.z = f2bf(v.z); o.w = f2bf(v.w);
    ((ushort4*)h)[(size_t)node * 64 + c] = o;
}

// ---------------- weight fp32 -> bf16 ----------------

__global__ void k_cvtw(const float* w0, const float* w1, const float* w2,
                       const float* w3, const float* w4, const float* w5,
                       const float* w6, u16* __restrict__ out) {
    int idx = blockIdx.x * blockDim.x + threadIdx.x;
    if (idx >= 7 * 65536) return;
    int m = idx >> 16, off = idx & 65535;
    const float* w = w0;
    if (m == 1) w = w1; else if (m == 2) w = w2; else if (m == 3) w = w3;
    else if (m == 4) w = w4; else if (m == 5) w = w5; else if (m == 6) w = w6;
    out[idx] = f2bf(w[off]);
}

// ---------------- mean aggregation over a 128-col half ----------------
// wave per node; 4 rows (edges) in parallel x unroll 4 = 16 rows in flight.
// 256B row-half = 2 full cache lines; working set per pass = 25.6 MB.

__global__ void k_agg_half(const u16* __restrict__ h, const int* __restrict__ offs,
                           const int* __restrict__ srcs, u16* __restrict__ out,
                           int colOff, int N) {
    int wid = (blockIdx.x * blockDim.x + threadIdx.x) >> 6;
    int lane = threadIdx.x & 63;
    if (wid >= N) return;
    int beg = offs[wid], end = offs[wid + 1];
    int q = lane >> 4;             // row slot 0..3
    int cl = lane & 15;            // 16B chunk within the 256B half-row
    const u16* hb = h + colOff + cl * 8;
    float acc[8];
    #pragma unroll
    for (int i = 0; i < 8; i++) acc[i] = 0.f;
    int e = beg + q;
    for (; e + 12 < end; e += 16) {
        int j0 = srcs[e], j1 = srcs[e + 4], j2 = srcs[e + 8], j3 = srcs[e + 12];
        ushort8 v0 = *(const ushort8*)&hb[(size_t)j0 * D];
        ushort8 v1 = *(const ushort8*)&hb[(size_t)j1 * D];
        ushort8 v2 = *(const ushort8*)&hb[(size_t)j2 * D];
        ushort8 v3 = *(const ushort8*)&hb[(size_t)j3 * D];
        #pragma unroll
        for (int i = 0; i < 8; i++)
            acc[i] += (bf2f(v0[i]) + bf2f(v1[i])) + (bf2f(v2[i]) + bf2f(v3[i]));
    }
    for (; e < end; e += 4) {
        int j = srcs[e];
        ushort8 v = *(const ushort8*)&hb[(size_t)j * D];
        #pragma unroll
        for (int i = 0; i < 8; i++) acc[i] += bf2f(v[i]);
    }
    #pragma unroll
    for (int i = 0; i < 8; i++) {
        acc[i] += __shfl_xor(acc[i], 16);
        acc[i] += __shfl_xor(acc[i], 32);
    }
    if (q == 0) {
        int dg = end - beg;
        float inv = 1.0f / (float)(dg < 1 ? 1 : dg);
        ushort8 o;
        #pragma unroll
        for (int i = 0; i < 8; i++) o[i] = f2bf(acc[i] * inv);
        *(ushort8*)&out[(size_t)wid * D + colOff + cl * 8] = o;
    }
}

// ---------------- fused MFMA GEMM ----------------
// out[M,256] = epi( sum_p Ap[M,256] @ Wp[256,256]^T + bias ), bf16 in, fp32 acc.
// BM=128, BN=256 (full width), BK=32; 512 thr = 8 waves (2x4); 16x16x32 bf16.

__global__ __launch_bounds__(512)
void k_fgemm(const u16* __restrict__ A0, const u16* __restrict__ W0,
             const u16* __restrict__ A1, const u16* __restrict__ W1,
             int npairs,
             const float* __restrict__ bias, const float* __restrict__ prelu_a,
             void* __restrict__ outp, int out_bf16, int M) {
    __shared__ u16 As[128 * 32];
    __shared__ u16 Bs[256 * 32];
    int t = threadIdx.x;
    int wave = t >> 6, lane = t & 63;
    int r = lane & 15, quad = lane >> 4;
    int wm = (wave & 1) * 64;
    int wn = (wave >> 1) * 64;
    int m0 = blockIdx.x * 128;

    f32x4 acc[4][4];
    #pragma unroll
    for (int i = 0; i < 4; i++)
        #pragma unroll
        for (int j = 0; j < 4; j++)
            acc[i][j] = (f32x4){0.f, 0.f, 0.f, 0.f};

    int rowA  = t >> 2,           colA  = (t & 3) * 8;
    int rowB1 = (t + 512) >> 2;
    u16* ldsA  = &As[wave * 512];
    u16* ldsB0 = &Bs[wave * 512];
    u16* ldsB1 = &Bs[4096 + wave * 512];

    for (int p = 0; p < npairs; ++p) {
        const u16* Ag = p ? A1 : A0;
        const u16* Wg = p ? W1 : W0;
        for (int kt = 0; kt < 8; ++kt) {
            int k0 = kt * 32;
            __syncthreads();
            load_lds16(Ag + (size_t)(m0 + rowA) * D + k0 + colA, ldsA);
            load_lds16(Wg + (size_t)rowA * D + k0 + colA, ldsB0);
            load_lds16(Wg + (size_t)rowB1 * D + k0 + colA, ldsB1);
            __syncthreads();

            short8 a[4], b[4];
            #pragma unroll
            for (int mt = 0; mt < 4; mt++)
                a[mt] = *(const short8*)&As[(wm + mt * 16 + r) * 32 + quad * 8];
            #pragma unroll
            for (int nt = 0; nt < 4; nt++)
                b[nt] = *(const short8*)&Bs[(wn + nt * 16 + r) * 32 + quad * 8];
            #pragma unroll
            for (int mt = 0; mt < 4; mt++)
                #pragma unroll
                for (int nt = 0; nt < 4; nt++)
                    acc[mt][nt] = __builtin_amdgcn_mfma_f32_16x16x32_bf16(
                        a[mt], b[nt], acc[mt][nt], 0, 0, 0);
        }
    }

    float pa = prelu_a ? *prelu_a : 0.f;
    int dop = prelu_a != nullptr;
    #pragma unroll
    for (int nt = 0; nt < 4; nt++) {
        int col = wn + nt * 16 + r;
        float bv = bias ? bias[col] : 0.f;
        #pragma unroll
        for (int mt = 0; mt < 4; mt++) {
            #pragma unroll
            for (int i = 0; i < 4; i++) {
                int row = m0 + wm + mt * 16 + quad * 4 + i;
                if (row < M) {
                    float v = acc[mt][nt][i] + bv;
                    if (dop) v = (v >= 0.f) ? v : pa * v;
                    if (out_bf16)
                        ((u16*)outp)[(size_t)row * D + col] = f2bf(v);
                    else
                        ((float*)outp)[(size_t)row * D + col] = v;
                }
            }
        }
    }
}

// ---------------- launcher ----------------

extern "C" void kernel_launch(void* const* d_in, const int* in_sizes, int n_in,
                              void* d_out, int out_size, void* d_ws, size_t ws_size,
                              hipStream_t stream) {
    const int*   x    = (const int*)d_in[0];
    const int*   ei   = (const int*)d_in[1];
    const float* emb  = (const float*)d_in[3];
    const float* Wl[3] = {(const float*)d_in[4],  (const float*)d_in[8],  (const float*)d_in[12]};
    const float* bl[3] = {(const float*)d_in[5],  (const float*)d_in[9],  (const float*)d_in[13]};
    const float* Wr[3] = {(const float*)d_in[6],  (const float*)d_in[10], (const float*)d_in[14]};
    const float* pa[3] = {(const float*)d_in[7],  (const float*)d_in[11], (const float*)d_in[15]};
    const float* Wout = (const float*)d_in[16];
    const float* bout = (const float*)d_in[17];

    int N = in_sizes[0];
    int E = in_sizes[1] / 2;
    const int* src = ei;
    const int* dst = ei + E;

    char* ws = (char*)d_ws;
    size_t off = 0;
    auto walloc = [&](size_t bytes) -> void* {
        void* p = ws + off;
        off += (bytes + 255) & ~(size_t)255;
        return p;
    };
    // tile staging over-reads up to ~49 KB past row M-1: keep activations mid-ws
    u16* hA   = (u16*)walloc((size_t)N * D * sizeof(u16));
    u16* hB   = (u16*)walloc((size_t)N * D * sizeof(u16));
    u16* mean = (u16*)walloc((size_t)N * D * sizeof(u16));
    u16* wbf  = (u16*)walloc((size_t)7 * 65536 * sizeof(u16));
    int* deg    = (int*)walloc((size_t)N * sizeof(int));
    int* offs   = (int*)walloc((size_t)(N + 1) * sizeof(int));
    int* cursor = (int*)walloc((size_t)N * sizeof(int));
    int* bsum   = (int*)walloc(4096);
    int* srcs   = (int*)walloc((size_t)E * sizeof(int));
    int* subcur = (int*)walloc((size_t)NB * SUBW * sizeof(int));
    unsigned* bins = (unsigned*)walloc((size_t)NB * SUBW * SUBCAP * sizeof(unsigned));

    u16* Wlb[3] = {wbf + 0 * 65536, wbf + 2 * 65536, wbf + 4 * 65536};
    u16* Wrb[3] = {wbf + 1 * 65536, wbf + 3 * 65536, wbf + 5 * 65536};
    u16* Woutb  = wbf + 6 * 65536;

    // --- weights -> bf16 ---
    k_cvtw<<<(7 * 65536 + 255) / 256, 256, 0, stream>>>(
        Wl[0], Wr[0], Wl[1], Wr[1], Wl[2], Wr[2], Wout, wbf);

    // --- CSR build (two-level) ---
    hipMemsetAsync(deg, 0, (size_t)N * sizeof(int), stream);
    int eb = (E + 255) / 256;
    int nb = (N + 1023) / 1024;
    k_initsub<<<(NB * SUBW + 255) / 256, 256, 0, stream>>>(subcur);
    k_bin<<<eb, 256, 0, stream>>>(src, dst, deg, subcur, bins, E);
    k_blocksum<<<nb, 256, 0, stream>>>(deg, bsum, N);
    k_scanbsum<<<1, 64, 0, stream>>>(bsum, nb, offs, N, E);
    k_scanwrite<<<nb, 256, 0, stream>>>(deg, bsum, offs, cursor, N);
    k_scat2<<<NB * SUBW, 256, 0, stream>>>(bins, subcur, cursor, srcs);

    // --- h0 = bf16(emb[x]) ---
    k_gather_bf<<<(N * 64 + 255) / 256, 256, 0, stream>>>(x, emb, hA, N);

    int mb   = (N + 127) / 128;
    int aggb = (N + 3) / 4;

    // layer 1: hA -> hB
    k_agg_half<<<aggb, 256, 0, stream>>>(hA, offs, srcs, mean, 0, N);
    k_agg_half<<<aggb, 256, 0, stream>>>(hA, offs, srcs, mean, 128, N);
    k_fgemm<<<mb, 512, 0, stream>>>(mean, Wlb[0], hA, Wrb[0], 2, bl[0], pa[0], hB, 1, N);
    // layer 2: hB -> hA
    k_agg_half<<<aggb, 256, 0, stream>>>(hB, offs, srcs, mean, 0, N);
    k_agg_half<<<aggb, 256, 0, stream>>>(hB, offs, srcs, mean, 128, N);
    k_fgemm<<<mb, 512, 0, stream>>>(mean, Wlb[1], hB, Wrb[1], 2, bl[1], pa[1], hA, 1, N);
    // layer 3: hA -> hB
    k_agg_half<<<aggb, 256, 0, stream>>>(hA, offs, srcs, mean, 0, N);
    k_agg_half<<<aggb, 256, 0, stream>>>(hA, offs, srcs, mean, 128, N);
    k_fgemm<<<mb, 512, 0, stream>>>(mean, Wlb[2], hA, Wrb[2], 2, bl[2], pa[2], hB, 1, N);
    // output projection -> fp32 d_out
    k_fgemm<<<mb, 512, 0, stream>>>(hB, Woutb, hB, Woutb, 1, bout, nullptr, d_out, 0, N);
}

// Round 5
// 1496.585 us; speedup vs baseline: 1.8290x; 1.8290x over previous
//
#include <hip/hip_runtime.h>

#define D 256
typedef unsigned short u16;
using short8  = __attribute__((ext_vector_type(8))) short;
using ushort8 = __attribute__((ext_vector_type(8))) unsigned short;
using f32x4   = __attribute__((ext_vector_type(4))) float;

#define BCHUNK 4096      // edges per binning block
#define BINCAP 140000    // per coarse-bin capacity (avg 131K, ~25 sigma margin)
#define NPB    40        // blocks per bin in hist/scatter phases

__device__ __forceinline__ u16 f2bf(float f) {
    unsigned u = __float_as_uint(f);
    unsigned r = (u + 0x7FFFu + ((u >> 16) & 1u)) >> 16;
    return (u16)r;
}
__device__ __forceinline__ float bf2f(u16 v) {
    return __uint_as_float(((unsigned)v) << 16);
}

__device__ __forceinline__ void load_lds16(const u16* g, u16* l) {
    __builtin_amdgcn_global_load_lds(
        (const __attribute__((address_space(1))) void*)g,
        (__attribute__((address_space(3))) void*)l, 16, 0, 0);
}

// ---------------- CSR build: local-hist + bulk-reserve binning ----------------

__global__ void k_initcur(int* __restrict__ bincur, int nbin) {
    int i = threadIdx.x;
    if (i < nbin) bincur[i] = i * BINCAP;
}

// Coarse-bin edges (4096-node ranges). Per block: LDS hist over its 4096-edge
// chunk, ONE global reserve atomic per bin (25/block), then ranked writes into
// per-bin contiguous segments.
__global__ void k_bin2(const int* __restrict__ src, const int* __restrict__ dst,
                       int* __restrict__ bincur, unsigned* __restrict__ bins, int E) {
    __shared__ int cnt[32];
    __shared__ int bpos[32];
    int t = threadIdx.x;
    int base = blockIdx.x * BCHUNK;
    if (t < 32) cnt[t] = 0;
    __syncthreads();
    int lim = E - base; if (lim > BCHUNK) lim = BCHUNK;
    for (int i = t; i < lim; i += 256)
        atomicAdd(&cnt[dst[base + i] >> 12], 1);
    __syncthreads();
    if (t < 32 && cnt[t] > 0) {
        bpos[t] = atomicAdd(&bincur[t], cnt[t]);
        cnt[t] = 0;
    }
    __syncthreads();
    for (int i = t; i < lim; i += 256) {
        int d = dst[base + i], s = src[base + i];
        int b = d >> 12;
        int r = atomicAdd(&cnt[b], 1);
        bins[(size_t)bpos[b] + r] = (unsigned)s | ((unsigned)(d & 4095) << 17);
    }
}

// degree histogram over binned edges; counter window per bin = 16 KB (L2-local)
__global__ void k_hist2(const unsigned* __restrict__ bins, const int* __restrict__ bincur,
                        int* __restrict__ deg) {
    int b = blockIdx.x / NPB, isl = blockIdx.x % NPB;
    int cnt = bincur[b] - b * BINCAP;
    int sl = (cnt + NPB - 1) / NPB;
    int beg = isl * sl, end = beg + sl; if (end > cnt) end = cnt;
    const unsigned* bp = bins + (size_t)b * BINCAP;
    for (int i = beg + threadIdx.x; i < end; i += 256)
        atomicAdd(&deg[(b << 12) + (int)(bp[i] >> 17)], 1);
}

// bin-local exclusive scan: offs live inside per-bin padded srcs regions,
// so no global scan is needed. Also writes ends and cursor.
__global__ void k_scan2(const int* __restrict__ deg, int* __restrict__ offs,
                        int* __restrict__ ends, int* __restrict__ cursor, int N) {
    __shared__ int s[256];
    int b = blockIdx.x, t = threadIdx.x;
    int nloc = N - (b << 12); if (nloc > 4096) nloc = 4096;
    int v[16], sum = 0;
    #pragma unroll
    for (int j = 0; j < 16; j++) {
        int l = t * 16 + j;
        v[j] = (l < nloc) ? deg[(b << 12) + l] : 0;
        sum += v[j];
    }
    s[t] = sum;
    __syncthreads();
    for (int o = 1; o < 256; o <<= 1) {
        int x = (t >= o) ? s[t - o] : 0;
        __syncthreads();
        s[t] += x;
        __syncthreads();
    }
    int excl = s[t] - sum + b * BINCAP;
    #pragma unroll
    for (int j = 0; j < 16; j++) {
        int l = t * 16 + j;
        if (l < nloc) {
            int g = (b << 12) + l;
            offs[g] = excl; cursor[g] = excl; ends[g] = excl + v[j];
            excl += v[j];
        }
    }
}

// scatter binned edges into CSR srcs; cursor window 16 KB + srcs window
// ~0.5 MB per bin, bin-major block order keeps it L2-resident.
__global__ void k_scat3(const unsigned* __restrict__ bins, const int* __restrict__ bincur,
                        int* __restrict__ cursor, int* __restrict__ srcs) {
    int b = blockIdx.x / NPB, isl = blockIdx.x % NPB;
    int cnt = bincur[b] - b * BINCAP;
    int sl = (cnt + NPB - 1) / NPB;
    int beg = isl * sl, end = beg + sl; if (end > cnt) end = cnt;
    const unsigned* bp = bins + (size_t)b * BINCAP;
    for (int i = beg + threadIdx.x; i < end; i += 256) {
        unsigned v = bp[i];
        int d = (b << 12) + (int)(v >> 17);
        int p = atomicAdd(&cursor[d], 1);
        srcs[p] = (int)(v & 0x1FFFFu);
    }
}

// ---------------- embedding gather -> bf16 ----------------

__global__ void k_gather_bf(const int* __restrict__ x, const float* __restrict__ emb,
                            u16* __restrict__ h, int N) {
    int idx = blockIdx.x * blockDim.x + threadIdx.x;
    if (idx >= N * 64) return;
    int node = idx >> 6, c = idx & 63;
    int s = x[node];
    float4 v = ((const float4*)emb)[(size_t)s * 64 + c];
    ushort4 o;
    o.x = f2bf(v.x); o.y = f2bf(v.y); o.z = f2bf(v.z); o.w = f2bf(v.w);
    ((ushort4*)h)[(size_t)node * 64 + c] = o;
}

// ---------------- weight fp32 -> bf16 ----------------

__global__ void k_cvtw(const float* w0, const float* w1, const float* w2,
                       const float* w3, const float* w4, const float* w5,
                       const float* w6, u16* __restrict__ out) {
    int idx = blockIdx.x * blockDim.x + threadIdx.x;
    if (idx >= 7 * 65536) return;
    int m = idx >> 16, off = idx & 65535;
    const float* w = w0;
    if (m == 1) w = w1; else if (m == 2) w = w2; else if (m == 3) w = w3;
    else if (m == 4) w = w4; else if (m == 5) w = w5; else if (m == 6) w = w6;
    out[idx] = f2bf(w[off]);
}

// ---------------- mean aggregation over a 128-col half ----------------
// wave per node; 4 rows x unroll 4 = 16 rows in flight; per-pass gather
// working set 25.6 MB.

__global__ void k_agg_half(const u16* __restrict__ h, const int* __restrict__ offs,
                           const int* __restrict__ ends, const int* __restrict__ srcs,
                           u16* __restrict__ out, int colOff, int N) {
    int wid = (blockIdx.x * blockDim.x + threadIdx.x) >> 6;
    int lane = threadIdx.x & 63;
    if (wid >= N) return;
    int beg = offs[wid], end = ends[wid];
    int q = lane >> 4;             // row slot 0..3
    int cl = lane & 15;            // 16B chunk within the 256B half-row
    const u16* hb = h + colOff + cl * 8;
    float acc[8];
    #pragma unroll
    for (int i = 0; i < 8; i++) acc[i] = 0.f;
    int e = beg + q;
    for (; e + 12 < end; e += 16) {
        int j0 = srcs[e], j1 = srcs[e + 4], j2 = srcs[e + 8], j3 = srcs[e + 12];
        ushort8 v0 = *(const ushort8*)&hb[(size_t)j0 * D];
        ushort8 v1 = *(const ushort8*)&hb[(size_t)j1 * D];
        ushort8 v2 = *(const ushort8*)&hb[(size_t)j2 * D];
        ushort8 v3 = *(const ushort8*)&hb[(size_t)j3 * D];
        #pragma unroll
        for (int i = 0; i < 8; i++)
            acc[i] += (bf2f(v0[i]) + bf2f(v1[i])) + (bf2f(v2[i]) + bf2f(v3[i]));
    }
    for (; e < end; e += 4) {
        int j = srcs[e];
        ushort8 v = *(const ushort8*)&hb[(size_t)j * D];
        #pragma unroll
        for (int i = 0; i < 8; i++) acc[i] += bf2f(v[i]);
    }
    #pragma unroll
    for (int i = 0; i < 8; i++) {
        acc[i] += __shfl_xor(acc[i], 16);
        acc[i] += __shfl_xor(acc[i], 32);
    }
    if (q == 0) {
        int dg = end - beg;
        float inv = 1.0f / (float)(dg < 1 ? 1 : dg);
        ushort8 o;
        #pragma unroll
        for (int i = 0; i < 8; i++) o[i] = f2bf(acc[i] * inv);
        *(ushort8*)&out[(size_t)wid * D + colOff + cl * 8] = o;
    }
}

// ---------------- fused MFMA GEMM ----------------
// out[M,256] = epi( sum_p Ap[M,256] @ Wp[256,256]^T + bias ), bf16 in, fp32 acc.
// BM=128, BN=256 (full width), BK=32; 512 thr = 8 waves (2x4); 16x16x32 bf16.

__global__ __launch_bounds__(512)
void k_fgemm(const u16* __restrict__ A0, const u16* __restrict__ W0,
             const u16* __restrict__ A1, const u16* __restrict__ W1,
             int npairs,
             const float* __restrict__ bias, const float* __restrict__ prelu_a,
             void* __restrict__ outp, int out_bf16, int M) {
    __shared__ u16 As[128 * 32];
    __shared__ u16 Bs[256 * 32];
    int t = threadIdx.x;
    int wave = t >> 6, lane = t & 63;
    int r = lane & 15, quad = lane >> 4;
    int wm = (wave & 1) * 64;
    int wn = (wave >> 1) * 64;
    int m0 = blockIdx.x * 128;

    f32x4 acc[4][4];
    #pragma unroll
    for (int i = 0; i < 4; i++)
        #pragma unroll
        for (int j = 0; j < 4; j++)
            acc[i][j] = (f32x4){0.f, 0.f, 0.f, 0.f};

    int rowA  = t >> 2,           colA  = (t & 3) * 8;
    int rowB1 = (t + 512) >> 2;
    u16* ldsA  = &As[wave * 512];
    u16* ldsB0 = &Bs[wave * 512];
    u16* ldsB1 = &Bs[4096 + wave * 512];

    for (int p = 0; p < npairs; ++p) {
        const u16* Ag = p ? A1 : A0;
        const u16* Wg = p ? W1 : W0;
        for (int kt = 0; kt < 8; ++kt) {
            int k0 = kt * 32;
            __syncthreads();
            load_lds16(Ag + (size_t)(m0 + rowA) * D + k0 + colA, ldsA);
            load_lds16(Wg + (size_t)rowA * D + k0 + colA, ldsB0);
            load_lds16(Wg + (size_t)rowB1 * D + k0 + colA, ldsB1);
            __syncthreads();

            short8 a[4], b[4];
            #pragma unroll
            for (int mt = 0; mt < 4; mt++)
                a[mt] = *(const short8*)&As[(wm + mt * 16 + r) * 32 + quad * 8];
            #pragma unroll
            for (int nt = 0; nt < 4; nt++)
                b[nt] = *(const short8*)&Bs[(wn + nt * 16 + r) * 32 + quad * 8];
            #pragma unroll
            for (int mt = 0; mt < 4; mt++)
                #pragma unroll
                for (int nt = 0; nt < 4; nt++)
                    acc[mt][nt] = __builtin_amdgcn_mfma_f32_16x16x32_bf16(
                        a[mt], b[nt], acc[mt][nt], 0, 0, 0);
        }
    }

    float pa = prelu_a ? *prelu_a : 0.f;
    int dop = prelu_a != nullptr;
    #pragma unroll
    for (int nt = 0; nt < 4; nt++) {
        int col = wn + nt * 16 + r;
        float bv = bias ? bias[col] : 0.f;
        #pragma unroll
        for (int mt = 0; mt < 4; mt++) {
            #pragma unroll
            for (int i = 0; i < 4; i++) {
                int row = m0 + wm + mt * 16 + quad * 4 + i;
                if (row < M) {
                    float v = acc[mt][nt][i] + bv;
                    if (dop) v = (v >= 0.f) ? v : pa * v;
                    if (out_bf16)
                        ((u16*)outp)[(size_t)row * D + col] = f2bf(v);
                    else
                        ((float*)outp)[(size_t)row * D + col] = v;
                }
            }
        }
    }
}

// ---------------- launcher ----------------

extern "C" void kernel_launch(void* const* d_in, const int* in_sizes, int n_in,
                              void* d_out, int out_size, void* d_ws, size_t ws_size,
                              hipStream_t stream) {
    const int*   x    = (const int*)d_in[0];
    const int*   ei   = (const int*)d_in[1];
    const float* emb  = (const float*)d_in[3];
    const float* Wl[3] = {(const float*)d_in[4],  (const float*)d_in[8],  (const float*)d_in[12]};
    const float* bl[3] = {(const float*)d_in[5],  (const float*)d_in[9],  (const float*)d_in[13]};
    const float* Wr[3] = {(const float*)d_in[6],  (const float*)d_in[10], (const float*)d_in[14]};
    const float* pa[3] = {(const float*)d_in[7],  (const float*)d_in[11], (const float*)d_in[15]};
    const float* Wout = (const float*)d_in[16];
    const float* bout = (const float*)d_in[17];

    int N = in_sizes[0];
    int E = in_sizes[1] / 2;
    const int* src = ei;
    const int* dst = ei + E;
    int nbin = (N + 4095) >> 12;   // 25 for N=100000

    char* ws = (char*)d_ws;
    size_t off = 0;
    auto walloc = [&](size_t bytes) -> void* {
        void* p = ws + off;
        off += (bytes + 255) & ~(size_t)255;
        return p;
    };
    // tile staging over-reads up to ~115 KB past row M-1: keep activations mid-ws
    u16* hA   = (u16*)walloc((size_t)N * D * sizeof(u16));
    u16* hB   = (u16*)walloc((size_t)N * D * sizeof(u16));
    u16* mean = (u16*)walloc((size_t)N * D * sizeof(u16));
    u16* wbf  = (u16*)walloc((size_t)7 * 65536 * sizeof(u16));
    int* deg    = (int*)walloc((size_t)N * sizeof(int));
    int* offs   = (int*)walloc((size_t)N * sizeof(int));
    int* ends   = (int*)walloc((size_t)N * sizeof(int));
    int* cursor = (int*)walloc((size_t)N * sizeof(int));
    int* bincur = (int*)walloc(256);
    unsigned* bins = (unsigned*)walloc((size_t)nbin * BINCAP * sizeof(unsigned));
    int* srcs   = (int*)walloc((size_t)nbin * BINCAP * sizeof(int));

    u16* Wlb[3] = {wbf + 0 * 65536, wbf + 2 * 65536, wbf + 4 * 65536};
    u16* Wrb[3] = {wbf + 1 * 65536, wbf + 3 * 65536, wbf + 5 * 65536};
    u16* Woutb  = wbf + 6 * 65536;

    // --- weights -> bf16 ---
    k_cvtw<<<(7 * 65536 + 255) / 256, 256, 0, stream>>>(
        Wl[0], Wr[0], Wl[1], Wr[1], Wl[2], Wr[2], Wout, wbf);

    // --- CSR build ---
    hipMemsetAsync(deg, 0, (size_t)N * sizeof(int), stream);
    k_initcur<<<1, 64, 0, stream>>>(bincur, nbin);
    int bb = (E + BCHUNK - 1) / BCHUNK;
    k_bin2<<<bb, 256, 0, stream>>>(src, dst, bincur, bins, E);
    k_hist2<<<nbin * NPB, 256, 0, stream>>>(bins, bincur, deg);
    k_scan2<<<nbin, 256, 0, stream>>>(deg, offs, ends, cursor, N);
    k_scat3<<<nbin * NPB, 256, 0, stream>>>(bins, bincur, cursor, srcs);

    // --- h0 = bf16(emb[x]) ---
    k_gather_bf<<<(N * 64 + 255) / 256, 256, 0, stream>>>(x, emb, hA, N);

    int mb   = (N + 127) / 128;
    int aggb = (N + 3) / 4;

    // layer 1: hA -> hB
    k_agg_half<<<aggb, 256, 0, stream>>>(hA, offs, ends, srcs, mean, 0, N);
    k_agg_half<<<aggb, 256, 0, stream>>>(hA, offs, ends, srcs, mean, 128, N);
    k_fgemm<<<mb, 512, 0, stream>>>(mean, Wlb[0], hA, Wrb[0], 2, bl[0], pa[0], hB, 1, N);
    // layer 2: hB -> hA
    k_agg_half<<<aggb, 256, 0, stream>>>(hB, offs, ends, srcs, mean, 0, N);
    k_agg_half<<<aggb, 256, 0, stream>>>(hB, offs, ends, srcs, mean, 128, N);
    k_fgemm<<<mb, 512, 0, stream>>>(mean, Wlb[1], hB, Wrb[1], 2, bl[1], pa[1], hA, 1, N);
    // layer 3: hA -> hB
    k_agg_half<<<aggb, 256, 0, stream>>>(hA, offs, ends, srcs, mean, 0, N);
    k_agg_half<<<aggb, 256, 0, stream>>>(hA, offs, ends, srcs, mean, 128, N);
    k_fgemm<<<mb, 512, 0, stream>>>(mean, Wlb[2], hA, Wrb[2], 2, bl[2], pa[2], hB, 1, N);
    // output projection -> fp32 d_out
    k_fgemm<<<mb, 512, 0, stream>>>(hB, Woutb, hB, Woutb, 1, bout, nullptr, d_out, 0, N);
}

// Round 6
// 1161.129 us; speedup vs baseline: 2.3574x; 1.2889x over previous
//
#include <hip/hip_runtime.h>

#define D 256
typedef unsigned short u16;
using short8  = __attribute__((ext_vector_type(8))) short;
using ushort8 = __attribute__((ext_vector_type(8))) unsigned short;
using f32x4   = __attribute__((ext_vector_type(4))) float;

#define BCHUNK  4096     // edges per binning block
#define FBINCAP 17500    // per fine-bin capacity (avg 16384, ~8.7 sigma margin)

__device__ __forceinline__ u16 f2bf(float f) {
    unsigned u = __float_as_uint(f);
    unsigned r = (u + 0x7FFFu + ((u >> 16) & 1u)) >> 16;
    return (u16)r;
}
__device__ __forceinline__ float bf2f(u16 v) {
    return __uint_as_float(((unsigned)v) << 16);
}

__device__ __forceinline__ void load_lds16(const u16* g, u16* l) {
    __builtin_amdgcn_global_load_lds(
        (const __attribute__((address_space(1))) void*)g,
        (__attribute__((address_space(3))) void*)l, 16, 0, 0);
}

// ---------------- CSR build ----------------

__global__ void k_initcur(int* __restrict__ bincur, int nfbin) {
    int i = threadIdx.x;
    if (i < nfbin) bincur[i] = i * FBINCAP;
}

// Fine-bin edges (512-node dst ranges). Per block: LDS hist over its 4096-edge
// chunk, one reserve atomic per touched bin (<=196/block), ranked contiguous
// writes into per-bin regions. pack = src(17b) | dst_local(9b)<<17.
__global__ __launch_bounds__(256)
void k_binf(const int* __restrict__ src, const int* __restrict__ dst,
            int* __restrict__ bincur, unsigned* __restrict__ bins,
            int E, int nfbin) {
    __shared__ int cnt[256];
    __shared__ int bpos[256];
    int t = threadIdx.x;
    int base = blockIdx.x * BCHUNK;
    cnt[t] = 0;
    __syncthreads();
    int lim = E - base; if (lim > BCHUNK) lim = BCHUNK;
    for (int i = t; i < lim; i += 256)
        atomicAdd(&cnt[dst[base + i] >> 9], 1);
    __syncthreads();
    if (t < nfbin) {
        int c = cnt[t];
        bpos[t] = c > 0 ? atomicAdd(&bincur[t], c) : 0;
    }
    __syncthreads();
    cnt[t] = 0;
    __syncthreads();
    for (int i = t; i < lim; i += 256) {
        int d = dst[base + i], s = src[base + i];
        int fb = d >> 9;
        int r = atomicAdd(&cnt[fb], 1);
        bins[(size_t)bpos[fb] + r] = (unsigned)s | ((unsigned)(d & 511) << 17);
    }
}

// One block per fine bin: LDS hist(512) -> LDS scan -> LDS placement ->
// coalesced streaming write of srcs + direct offs/ends (padded CSR).
// All random access stays in LDS; zero global scatter.
__global__ __launch_bounds__(256)
void k_csrf(const unsigned* __restrict__ bins, const int* __restrict__ bincur,
            int* __restrict__ offs, int* __restrict__ ends,
            int* __restrict__ srcs, int N) {
    __shared__ int cnt[512];
    __shared__ int cur[512];
    __shared__ int ssum[256];
    __shared__ int loc[FBINCAP];
    int b = blockIdx.x, t = threadIdx.x;
    int bbase = b * FBINCAP;
    int ecnt = bincur[b] - bbase;
    cnt[t] = 0; cnt[t + 256] = 0;
    __syncthreads();
    const unsigned* bp = bins + bbase;
    for (int i = t; i < ecnt; i += 256)
        atomicAdd(&cnt[bp[i] >> 17], 1);
    __syncthreads();
    int a0 = cnt[2 * t], a1 = cnt[2 * t + 1];
    ssum[t] = a0 + a1;
    __syncthreads();
    for (int o = 1; o < 256; o <<= 1) {
        int x = (t >= o) ? ssum[t - o] : 0;
        __syncthreads();
        ssum[t] += x;
        __syncthreads();
    }
    int excl = ssum[t] - (a0 + a1);
    cur[2 * t] = excl;
    cur[2 * t + 1] = excl + a0;
    int nbase = b << 9;
    int l0 = nbase + 2 * t, l1 = l0 + 1;
    if (l0 < N) { offs[l0] = bbase + excl;      ends[l0] = bbase + excl + a0; }
    if (l1 < N) { offs[l1] = bbase + excl + a0; ends[l1] = bbase + excl + a0 + a1; }
    __syncthreads();
    for (int i = t; i < ecnt; i += 256) {
        unsigned v = bp[i];
        int p = atomicAdd(&cur[v >> 17], 1);
        loc[p] = (int)(v & 0x1FFFFu);
    }
    __syncthreads();
    for (int i = t; i < ecnt; i += 256)
        srcs[bbase + i] = loc[i];
}

// ---------------- embedding gather -> bf16 ----------------

__global__ void k_gather_bf(const int* __restrict__ x, const float* __restrict__ emb,
                            u16* __restrict__ h, int N) {
    int idx = blockIdx.x * blockDim.x + threadIdx.x;
    if (idx >= N * 64) return;
    int node = idx >> 6, c = idx & 63;
    int s = x[node];
    float4 v = ((const float4*)emb)[(size_t)s * 64 + c];
    ushort4 o;
    o.x = f2bf(v.x); o.y = f2bf(v.y); o.z = f2bf(v.z); o.w = f2bf(v.w);
    ((ushort4*)h)[(size_t)node * 64 + c] = o;
}

// ---------------- weight fp32 -> bf16 ----------------

__global__ void k_cvtw(const float* w0, const float* w1, const float* w2,
                       const float* w3, const float* w4, const float* w5,
                       const float* w6, u16* __restrict__ out) {
    int idx = blockIdx.x * blockDim.x + threadIdx.x;
    if (idx >= 7 * 65536) return;
    int m = idx >> 16, off = idx & 65535;
    const float* w = w0;
    if (m == 1) w = w1; else if (m == 2) w = w2; else if (m == 3) w = w3;
    else if (m == 4) w = w4; else if (m == 5) w = w5; else if (m == 6) w = w6;
    out[idx] = f2bf(w[off]);
}

// ---------------- mean aggregation over a 128-col half ----------------

__global__ void k_agg_half(const u16* __restrict__ h, const int* __restrict__ offs,
                           const int* __restrict__ ends, const int* __restrict__ srcs,
                           u16* __restrict__ out, int colOff, int N) {
    int wid = (blockIdx.x * blockDim.x + threadIdx.x) >> 6;
    int lane = threadIdx.x & 63;
    if (wid >= N) return;
    int beg = offs[wid], end = ends[wid];
    int q = lane >> 4;             // row slot 0..3
    int cl = lane & 15;            // 16B chunk within the 256B half-row
    const u16* hb = h + colOff + cl * 8;
    float acc[8];
    #pragma unroll
    for (int i = 0; i < 8; i++) acc[i] = 0.f;
    int e = beg + q;
    for (; e + 12 < end; e += 16) {
        int j0 = srcs[e], j1 = srcs[e + 4], j2 = srcs[e + 8], j3 = srcs[e + 12];
        ushort8 v0 = *(const ushort8*)&hb[(size_t)j0 * D];
        ushort8 v1 = *(const ushort8*)&hb[(size_t)j1 * D];
        ushort8 v2 = *(const ushort8*)&hb[(size_t)j2 * D];
        ushort8 v3 = *(const ushort8*)&hb[(size_t)j3 * D];
        #pragma unroll
        for (int i = 0; i < 8; i++)
            acc[i] += (bf2f(v0[i]) + bf2f(v1[i])) + (bf2f(v2[i]) + bf2f(v3[i]));
    }
    for (; e < end; e += 4) {
        int j = srcs[e];
        ushort8 v = *(const ushort8*)&hb[(size_t)j * D];
        #pragma unroll
        for (int i = 0; i < 8; i++) acc[i] += bf2f(v[i]);
    }
    #pragma unroll
    for (int i = 0; i < 8; i++) {
        acc[i] += __shfl_xor(acc[i], 16);
        acc[i] += __shfl_xor(acc[i], 32);
    }
    if (q == 0) {
        int dg = end - beg;
        float inv = 1.0f / (float)(dg < 1 ? 1 : dg);
        ushort8 o;
        #pragma unroll
        for (int i = 0; i < 8; i++) o[i] = f2bf(acc[i] * inv);
        *(ushort8*)&out[(size_t)wid * D + colOff + cl * 8] = o;
    }
}

// ---------------- fused MFMA GEMM ----------------
// out[M,256] = epi( sum_p Ap[M,256] @ Wp[256,256]^T + bias ), bf16 in, fp32 acc.
// BM=128, BN=256 (full width), BK=32; 512 thr = 8 waves (2x4); 16x16x32 bf16.

__global__ __launch_bounds__(512)
void k_fgemm(const u16* __restrict__ A0, const u16* __restrict__ W0,
             const u16* __restrict__ A1, const u16* __restrict__ W1,
             int npairs,
             const float* __restrict__ bias, const float* __restrict__ prelu_a,
             void* __restrict__ outp, int out_bf16, int M) {
    __shared__ u16 As[128 * 32];
    __shared__ u16 Bs[256 * 32];
    int t = threadIdx.x;
    int wave = t >> 6, lane = t & 63;
    int r = lane & 15, quad = lane >> 4;
    int wm = (wave & 1) * 64;
    int wn = (wave >> 1) * 64;
    int m0 = blockIdx.x * 128;

    f32x4 acc[4][4];
    #pragma unroll
    for (int i = 0; i < 4; i++)
        #pragma unroll
        for (int j = 0; j < 4; j++)
            acc[i][j] = (f32x4){0.f, 0.f, 0.f, 0.f};

    int rowA  = t >> 2,           colA  = (t & 3) * 8;
    int rowB1 = (t + 512) >> 2;
    u16* ldsA  = &As[wave * 512];
    u16* ldsB0 = &Bs[wave * 512];
    u16* ldsB1 = &Bs[4096 + wave * 512];

    for (int p = 0; p < npairs; ++p) {
        const u16* Ag = p ? A1 : A0;
        const u16* Wg = p ? W1 : W0;
        for (int kt = 0; kt < 8; ++kt) {
            int k0 = kt * 32;
            __syncthreads();
            load_lds16(Ag + (size_t)(m0 + rowA) * D + k0 + colA, ldsA);
            load_lds16(Wg + (size_t)rowA * D + k0 + colA, ldsB0);
            load_lds16(Wg + (size_t)rowB1 * D + k0 + colA, ldsB1);
            __syncthreads();

            short8 a[4], b[4];
            #pragma unroll
            for (int mt = 0; mt < 4; mt++)
                a[mt] = *(const short8*)&As[(wm + mt * 16 + r) * 32 + quad * 8];
            #pragma unroll
            for (int nt = 0; nt < 4; nt++)
                b[nt] = *(const short8*)&Bs[(wn + nt * 16 + r) * 32 + quad * 8];
            #pragma unroll
            for (int mt = 0; mt < 4; mt++)
                #pragma unroll
                for (int nt = 0; nt < 4; nt++)
                    acc[mt][nt] = __builtin_amdgcn_mfma_f32_16x16x32_bf16(
                        a[mt], b[nt], acc[mt][nt], 0, 0, 0);
        }
    }

    float pa = prelu_a ? *prelu_a : 0.f;
    int dop = prelu_a != nullptr;
    #pragma unroll
    for (int nt = 0; nt < 4; nt++) {
        int col = wn + nt * 16 + r;
        float bv = bias ? bias[col] : 0.f;
        #pragma unroll
        for (int mt = 0; mt < 4; mt++) {
            #pragma unroll
            for (int i = 0; i < 4; i++) {
                int row = m0 + wm + mt * 16 + quad * 4 + i;
                if (row < M) {
                    float v = acc[mt][nt][i] + bv;
                    if (dop) v = (v >= 0.f) ? v : pa * v;
                    if (out_bf16)
                        ((u16*)outp)[(size_t)row * D + col] = f2bf(v);
                    else
                        ((float*)outp)[(size_t)row * D + col] = v;
                }
            }
        }
    }
}

// ---------------- launcher ----------------

extern "C" void kernel_launch(void* const* d_in, const int* in_sizes, int n_in,
                              void* d_out, int out_size, void* d_ws, size_t ws_size,
                              hipStream_t stream) {
    const int*   x    = (const int*)d_in[0];
    const int*   ei   = (const int*)d_in[1];
    const float* emb  = (const float*)d_in[3];
    const float* Wl[3] = {(const float*)d_in[4],  (const float*)d_in[8],  (const float*)d_in[12]};
    const float* bl[3] = {(const float*)d_in[5],  (const float*)d_in[9],  (const float*)d_in[13]};
    const float* Wr[3] = {(const float*)d_in[6],  (const float*)d_in[10], (const float*)d_in[14]};
    const float* pa[3] = {(const float*)d_in[7],  (const float*)d_in[11], (const float*)d_in[15]};
    const float* Wout = (const float*)d_in[16];
    const float* bout = (const float*)d_in[17];

    int N = in_sizes[0];
    int E = in_sizes[1] / 2;
    const int* src = ei;
    const int* dst = ei + E;
    int nfbin = (N + 511) >> 9;    // 196 for N=100000

    char* ws = (char*)d_ws;
    size_t off = 0;
    auto walloc = [&](size_t bytes) -> void* {
        void* p = ws + off;
        off += (bytes + 255) & ~(size_t)255;
        return p;
    };
    // tile staging over-reads up to ~49 KB past row M-1: keep activations mid-ws
    u16* hA   = (u16*)walloc((size_t)N * D * sizeof(u16));
    u16* hB   = (u16*)walloc((size_t)N * D * sizeof(u16));
    u16* mean = (u16*)walloc((size_t)N * D * sizeof(u16));
    u16* wbf  = (u16*)walloc((size_t)7 * 65536 * sizeof(u16));
    int* offs   = (int*)walloc((size_t)N * sizeof(int));
    int* ends   = (int*)walloc((size_t)N * sizeof(int));
    int* bincur = (int*)walloc(1024);
    unsigned* bins = (unsigned*)walloc((size_t)nfbin * FBINCAP * sizeof(unsigned));
    int* srcs   = (int*)walloc((size_t)nfbin * FBINCAP * sizeof(int));

    u16* Wlb[3] = {wbf + 0 * 65536, wbf + 2 * 65536, wbf + 4 * 65536};
    u16* Wrb[3] = {wbf + 1 * 65536, wbf + 3 * 65536, wbf + 5 * 65536};
    u16* Woutb  = wbf + 6 * 65536;

    // --- weights -> bf16 ---
    k_cvtw<<<(7 * 65536 + 255) / 256, 256, 0, stream>>>(
        Wl[0], Wr[0], Wl[1], Wr[1], Wl[2], Wr[2], Wout, wbf);

    // --- CSR build: fine-bin + in-LDS sort ---
    k_initcur<<<1, 256, 0, stream>>>(bincur, nfbin);
    int bb = (E + BCHUNK - 1) / BCHUNK;
    k_binf<<<bb, 256, 0, stream>>>(src, dst, bincur, bins, E, nfbin);
    k_csrf<<<nfbin, 256, 0, stream>>>(bins, bincur, offs, ends, srcs, N);

    // --- h0 = bf16(emb[x]) ---
    k_gather_bf<<<(N * 64 + 255) / 256, 256, 0, stream>>>(x, emb, hA, N);

    int mb   = (N + 127) / 128;
    int aggb = (N + 3) / 4;

    // layer 1: hA -> hB
    k_agg_half<<<aggb, 256, 0, stream>>>(hA, offs, ends, srcs, mean, 0, N);
    k_agg_half<<<aggb, 256, 0, stream>>>(hA, offs, ends, srcs, mean, 128, N);
    k_fgemm<<<mb, 512, 0, stream>>>(mean, Wlb[0], hA, Wrb[0], 2, bl[0], pa[0], hB, 1, N);
    // layer 2: hB -> hA
    k_agg_half<<<aggb, 256, 0, stream>>>(hB, offs, ends, srcs, mean, 0, N);
    k_agg_half<<<aggb, 256, 0, stream>>>(hB, offs, ends, srcs, mean, 128, N);
    k_fgemm<<<mb, 512, 0, stream>>>(mean, Wlb[1], hB, Wrb[1], 2, bl[1], pa[1], hA, 1, N);
    // layer 3: hA -> hB
    k_agg_half<<<aggb, 256, 0, stream>>>(hA, offs, ends, srcs, mean, 0, N);
    k_agg_half<<<aggb, 256, 0, stream>>>(hA, offs, ends, srcs, mean, 128, N);
    k_fgemm<<<mb, 512, 0, stream>>>(mean, Wlb[2], hA, Wrb[2], 2, bl[2], pa[2], hB, 1, N);
    // output projection -> fp32 d_out
    k_fgemm<<<mb, 512, 0, stream>>>(hB, Woutb, hB, Woutb, 1, bout, nullptr, d_out, 0, N);
}